// Round 1
// 171.602 us; speedup vs baseline: 1.0300x; 1.0300x over previous
//
#include <hip/hip_runtime.h>

#define BB 8
#define SS 4096
#define DD 256
#define NEGV -1000000000.0f
#define NCH (SS / 32)  // 128 s-chunks of 32

typedef float f32x4 __attribute__((ext_vector_type(4)));
typedef short s16x8 __attribute__((ext_vector_type(8)));

// float -> bf16 round-to-nearest-even (inputs finite)
static __device__ __forceinline__ unsigned short f2bf(float x) {
  unsigned int u = __builtin_bit_cast(unsigned int, x);
  u += 0x7fffu + ((u >> 16) & 1u);
  return (unsigned short)(u >> 16);
}

// async global->LDS, 16B per lane; LDS dest = wave-uniform base + lane*16
static __device__ __forceinline__ void gload_lds16(
    const unsigned short* __restrict__ g, unsigned short* l) {
  __builtin_amdgcn_global_load_lds(
      (const __attribute__((address_space(1))) void*)g,
      (__attribute__((address_space(3))) void*)l, 16, 0, 0);
}

// ---------------------------------------------------------------------------
// prep: grid (S/32, B, 3), 256 thr, __launch_bounds__(256,4) -> 4 blocks/CU.
//  z=0: QS[b][s][d] = bf16(mask ? NEG : q/|q|^2)   (natural, no LDS)
//  z=1: KT chunked transpose: KT[((b*NCH+sc)*D + d)*32 + s'] = bf16(k/|k|^2)
//  z=2: VT same layout = bf16(v)
// 32-row blocks: 8 float4 loads/thread (~64 live VGPR) -> loads genuinely
// stay in flight (R-prev: 16-load version was register-chunked at VGPR=76,
// latency-serialized to 2 TB/s). Chunked layout makes the transposed flush
// wave-contiguous (4KB/wave) instead of 64x128B scattered at 8KB stride.
// ---------------------------------------------------------------------------
__global__ __launch_bounds__(256, 4) void prep_kernel(
    const float* __restrict__ Q, const float* __restrict__ K,
    const float* __restrict__ V, const int* __restrict__ mask,
    unsigned short* __restrict__ QS, unsigned short* __restrict__ KT,
    unsigned short* __restrict__ VT) {
  __shared__ unsigned short tile[32 * 260];
  const int b = blockIdx.y;
  const int sc = blockIdx.x;
  const int s0 = sc * 32;
  const int tid = threadIdx.x;
  const int w = tid >> 6, l = tid & 63;

  if (blockIdx.z == 0) {  // ---- Q: streaming, no LDS, no barrier
    float4 reg[8];
    float ps[8];
#pragma unroll
    for (int it = 0; it < 8; ++it) {
      const int row = it * 4 + w;
      reg[it] = *(const float4*)(Q + ((size_t)b * SS + s0 + row) * DD + l * 4);
    }
    int mk[8];
#pragma unroll
    for (int it = 0; it < 8; ++it) mk[it] = mask[b * SS + s0 + it * 4 + w];
#pragma unroll
    for (int it = 0; it < 8; ++it)
      ps[it] = reg[it].x * reg[it].x + reg[it].y * reg[it].y +
               reg[it].z * reg[it].z + reg[it].w * reg[it].w;
#pragma unroll
    for (int off = 32; off; off >>= 1)
#pragma unroll
      for (int it = 0; it < 8; ++it) ps[it] += __shfl_xor(ps[it], off);
#pragma unroll
    for (int it = 0; it < 8; ++it) {
      const int row = it * 4 + w;
      const float ca = mk[it] ? 0.0f : (1.0f / ps[it]);
      const float aa = mk[it] ? NEGV : 0.0f;
      ushort4 o;
      o.x = f2bf(reg[it].x * ca + aa);
      o.y = f2bf(reg[it].y * ca + aa);
      o.z = f2bf(reg[it].z * ca + aa);
      o.w = f2bf(reg[it].w * ca + aa);
      *(ushort4*)(QS + ((size_t)b * SS + s0 + row) * DD + l * 4) = o;
    }
    return;
  }

  const int isK = (blockIdx.z == 1);
  const float* __restrict__ src = isK ? K : V;
  unsigned short* __restrict__ dst = isK ? KT : VT;

  float4 reg[8];
  float ps[8];
#pragma unroll
  for (int it = 0; it < 8; ++it) {
    const int row = it * 4 + w;
    reg[it] = *(const float4*)(src + ((size_t)b * SS + s0 + row) * DD + l * 4);
  }
#pragma unroll
  for (int it = 0; it < 8; ++it)
    ps[it] = reg[it].x * reg[it].x + reg[it].y * reg[it].y +
             reg[it].z * reg[it].z + reg[it].w * reg[it].w;
  float scl[8];
  if (isK) {
#pragma unroll
    for (int off = 32; off; off >>= 1)
#pragma unroll
      for (int it = 0; it < 8; ++it) ps[it] += __shfl_xor(ps[it], off);
#pragma unroll
    for (int it = 0; it < 8; ++it) scl[it] = 1.0f / ps[it];
  } else {
#pragma unroll
    for (int it = 0; it < 8; ++it) scl[it] = 1.0f;
  }
#pragma unroll
  for (int it = 0; it < 8; ++it) {
    const int row = it * 4 + w;
    ushort4 o;
    o.x = f2bf(reg[it].x * scl[it]);
    o.y = f2bf(reg[it].y * scl[it]);
    o.z = f2bf(reg[it].z * scl[it]);
    o.w = f2bf(reg[it].w * scl[it]);
    *(ushort4*)(tile + row * 260 + l * 4) = o;
  }
  __syncthreads();
  // flush: thread tid owns d-row tid; 32 bf16 = 64B contiguous per thread;
  // chunked layout -> a wave's 64 threads write 4KB fully contiguous.
  const size_t gbase = ((size_t)(b * NCH + sc) * DD + tid) * 32;
#pragma unroll
  for (int c = 0; c < 4; ++c) {
    union { unsigned short h[8]; uint4 v; } u;
#pragma unroll
    for (int j = 0; j < 8; ++j) u.h[j] = tile[(c * 8 + j) * 260 + tid];
    *(uint4*)(dst + gbase + c * 8) = u.v;
  }
}

// ---------------------------------------------------------------------------
// p2: part[y][b][e][d] = sum_{s in chunk y} VT[e][s]*KT[d][s].
// KT/VT are s-chunked: element (d, s) lives at ((b*NCH + s/32)*D + d)*32 + s%32,
// so each gload_lds call reads a contiguous 1KB block (source offset = lane*16B
// exactly) and a k-step's operand is one contiguous 16KB chunk region.
// LDS layout/fragment indexing identical to previous (verified) version:
// kh-buffers of stride 32 hw, bank-uniform ds_read_b128.
// ---------------------------------------------------------------------------
__global__ __launch_bounds__(256) void p2_kernel(
    const unsigned short* __restrict__ KT, const unsigned short* __restrict__ VT,
    float* __restrict__ part, int iters) {
  __shared__ unsigned short vt_l[2][128 * 32];
  __shared__ unsigned short kt_l[2][128 * 32];
  const int b = blockIdx.z;
  const int d0 = (blockIdx.x & 1) * 128;
  const int e0 = (blockIdx.x >> 1) * 128;
  const int tid = threadIdx.x;
  const int w = tid >> 6, l = tid & 63;
  const int wr = w & 1, wc = w >> 1;
  const int quad = l >> 4, mr = l & 15;

  f32x4 acc[4][4];
#pragma unroll
  for (int i = 0; i < 4; ++i)
#pragma unroll
    for (int j = 0; j < 4; ++j) acc[i][j] = (f32x4){0.f, 0.f, 0.f, 0.f};

  for (int ks = 0; ks < iters; ++ks) {
    const int c0 = (blockIdx.y * iters + ks) * 2;  // 32-wide chunk index
#pragma unroll
    for (int h = 0; h < 2; ++h) {
      const size_t vch = ((size_t)(b * NCH + c0 + h) * DD + e0) * 32 + l * 8;
      const size_t kch = ((size_t)(b * NCH + c0 + h) * DD + d0) * 32 + l * 8;
#pragma unroll
      for (int g = 0; g < 2; ++g) {
        const int r0 = w * 32 + g * 16;
        gload_lds16(VT + vch + (size_t)r0 * 32, &vt_l[h][r0 * 32]);
        gload_lds16(KT + kch + (size_t)r0 * 32, &kt_l[h][r0 * 32]);
      }
    }
    __syncthreads();
#pragma unroll
    for (int kh = 0; kh < 2; ++kh) {
      s16x8 af[4], bfr[4];
#pragma unroll
      for (int i = 0; i < 4; ++i)
        af[i] = *(const s16x8*)(&vt_l[kh][(wr * 64 + i * 16 + mr) * 32 + quad * 8]);
#pragma unroll
      for (int j = 0; j < 4; ++j)
        bfr[j] = *(const s16x8*)(&kt_l[kh][(wc * 64 + j * 16 + mr) * 32 + quad * 8]);
#pragma unroll
      for (int i = 0; i < 4; ++i)
#pragma unroll
        for (int j = 0; j < 4; ++j)
          acc[i][j] = __builtin_amdgcn_mfma_f32_16x16x32_bf16(af[i], bfr[j],
                                                              acc[i][j], 0, 0, 0);
    }
    __syncthreads();
  }

  float* pb = part + ((size_t)blockIdx.y * BB + b) * DD * DD;
#pragma unroll
  for (int i = 0; i < 4; ++i) {
    const int e = e0 + wr * 64 + i * 16 + quad * 4;
#pragma unroll
    for (int j = 0; j < 4; ++j) {
      const int d = d0 + wc * 64 + j * 16 + mr;
      float* p = pb + (size_t)e * DD + d;
#pragma unroll
      for (int r = 0; r < 4; ++r) p[(size_t)r * DD] = acc[i][j][r];
    }
  }
}

// ---------------------------------------------------------------------------
// reduce: s1b[b][e][d] (bf16) = sum_p part[p][b][e][d]. L2/L3-resident.
// ---------------------------------------------------------------------------
__global__ __launch_bounds__(256) void reduce_kernel(
    const float* __restrict__ part, unsigned short* __restrict__ s1b,
    int split) {
  const size_t i4 = ((size_t)blockIdx.x * 256 + threadIdx.x) * 4;
  float ax = 0.f, ay = 0.f, az = 0.f, aw = 0.f;
  for (int p = 0; p < split; ++p) {
    const float4 v = *(const float4*)(part + (size_t)p * (BB * DD * DD) + i4);
    ax += v.x; ay += v.y; az += v.z; aw += v.w;
  }
  ushort4 o;
  o.x = f2bf(ax); o.y = f2bf(ay); o.z = f2bf(az); o.w = f2bf(aw);
  *(ushort4*)(s1b + i4) = o;
}

// ---------------------------------------------------------------------------
// p3: out[b][s][e] = (1/D) * sum_d QS[s][d] * s1b[e][d]. Same kh-split LDS.
// QS/s1b stay natural-layout (rows are 512B, staging already line-coalesced).
// ---------------------------------------------------------------------------
__global__ __launch_bounds__(256) void p3_kernel(
    const unsigned short* __restrict__ QS, const unsigned short* __restrict__ s1b,
    float* __restrict__ out) {
  __shared__ unsigned short qs_l[2][128 * 32];
  __shared__ unsigned short s1_l[2][128 * 32];
  const int b = blockIdx.z;
  const int e0 = blockIdx.x * 128;
  const int s0 = blockIdx.y * 128;
  const int tid = threadIdx.x;
  const int w = tid >> 6, l = tid & 63;
  const int wr = w & 1, wc = w >> 1;
  const int quad = l >> 4, mr = l & 15;
  const int lr = l >> 2;
  const int lc = (l & 3) * 8;

  f32x4 acc[4][4];
#pragma unroll
  for (int i = 0; i < 4; ++i)
#pragma unroll
    for (int j = 0; j < 4; ++j) acc[i][j] = (f32x4){0.f, 0.f, 0.f, 0.f};

  for (int ks = 0; ks < 4; ++ks) {
    const int dc = ks * 64;
#pragma unroll
    for (int h = 0; h < 2; ++h)
#pragma unroll
      for (int g = 0; g < 2; ++g) {
        const int r0 = w * 32 + g * 16;
        gload_lds16(QS + ((size_t)b * SS + s0 + r0 + lr) * DD + dc + h * 32 + lc,
                    &qs_l[h][r0 * 32]);
        gload_lds16(s1b + ((size_t)b * DD + e0 + r0 + lr) * DD + dc + h * 32 + lc,
                    &s1_l[h][r0 * 32]);
      }
    __syncthreads();
#pragma unroll
    for (int kh = 0; kh < 2; ++kh) {
      s16x8 af[4], bfr[4];
#pragma unroll
      for (int i = 0; i < 4; ++i)
        af[i] = *(const s16x8*)(&qs_l[kh][(wr * 64 + i * 16 + mr) * 32 + quad * 8]);
#pragma unroll
      for (int j = 0; j < 4; ++j)
        bfr[j] = *(const s16x8*)(&s1_l[kh][(wc * 64 + j * 16 + mr) * 32 + quad * 8]);
#pragma unroll
      for (int i = 0; i < 4; ++i)
#pragma unroll
        for (int j = 0; j < 4; ++j)
          acc[i][j] = __builtin_amdgcn_mfma_f32_16x16x32_bf16(af[i], bfr[j],
                                                              acc[i][j], 0, 0, 0);
    }
    __syncthreads();
  }

#pragma unroll
  for (int i = 0; i < 4; ++i) {
    const int s = s0 + wr * 64 + i * 16 + quad * 4;
#pragma unroll
    for (int j = 0; j < 4; ++j) {
      const int e = e0 + wc * 64 + j * 16 + mr;
      float* p = out + ((size_t)b * SS + s) * DD + e;
#pragma unroll
      for (int r = 0; r < 4; ++r) p[(size_t)r * DD] = acc[i][j][r] * (1.0f / DD);
    }
  }
}

extern "C" void kernel_launch(void* const* d_in, const int* in_sizes, int n_in,
                              void* d_out, int out_size, void* d_ws,
                              size_t ws_size, hipStream_t stream) {
  const float* Q = (const float*)d_in[0];
  const float* K = (const float*)d_in[1];
  const float* V = (const float*)d_in[2];
  const int* mask = (const int*)d_in[3];
  float* out = (float*)d_out;

  char* ws = (char*)d_ws;
  const size_t MB = (size_t)1024 * 1024;
  unsigned short* QS = (unsigned short*)(ws);            // bf16 [B][S][D] 16MB
  unsigned short* KT = (unsigned short*)(ws + 16 * MB);  // bf16 chunked 16MB
  unsigned short* VT = (unsigned short*)(ws + 32 * MB);  // bf16 chunked 16MB
  float* part = (float*)(ws + 48 * MB);                  // f32 [split][B][D][D]

  const int split = (ws_size >= (size_t)82 * MB) ? 16 : 8;
  const int iters = SS / (64 * split);  // K-chunks of 64 per p2 block
  unsigned short* s1b =
      (unsigned short*)(ws + 48 * MB + (size_t)split * 2 * MB);  // bf16 1MB

  prep_kernel<<<dim3(SS / 32, BB, 3), 256, 0, stream>>>(Q, K, V, mask, QS, KT,
                                                        VT);
  p2_kernel<<<dim3(4, split, BB), 256, 0, stream>>>(KT, VT, part, iters);
  reduce_kernel<<<dim3(512), 256, 0, stream>>>(part, s1b, split);
  p3_kernel<<<dim3(2, SS / 128, BB), 256, 0, stream>>>(QS, s1b, out);
}